// Round 1
// baseline (86.453 us; speedup 1.0000x reference)
//
#include <hip/hip_runtime.h>
#include <hip/hip_bf16.h>

// Problem constants (from reference): B=128, A=128, D=8, F=256, BF=16 (bonds unused)
#define NB 128
#define NA 128
#define ND 8
#define NF 256
#define NF4 (NF / 4)   // 64 float4 per feature row

// One wave (64 lanes) per atom: lane i owns float4 i of the 256-float row.
// Block = 256 threads = 4 atoms. Edges are wave-uniform -> no divergence.
__global__ __launch_bounds__(256) void NeuralGraphPool_52072183497147_kernel(
        const float4* __restrict__ atoms,   // (B, A, F) as float4 rows
        const int*    __restrict__ edges,   // (B, A, D)
        float4*       __restrict__ out)     // (B, A, F)
{
    const int tid   = threadIdx.x;
    const int lane  = tid & 63;                       // float4 index in row
    const int aIdx  = (blockIdx.x << 2) + (tid >> 6); // global atom index b*A + a
    const int b     = aIdx >> 7;                      // / NA
    const int base  = aIdx * NF4;

    // self feature
    float4 v = atoms[base + lane];

    const int* e = edges + aIdx * ND;
    int deg = 0;

    #pragma unroll
    for (int d = 0; d < ND; ++d) {
        const int ed   = e[d];
        const bool ok  = (ed >= 0);
        deg += ok ? 1 : 0;
        // padding edge: reference gathers the zero pad-row -> contributes 0.0 to max.
        // Branch-free: load a valid row (row 0 of this batch) and scale by 0.
        const int row  = ok ? ed : 0;
        const float m  = ok ? 1.0f : 0.0f;
        const float4 n = atoms[((b << 7) + row) * NF4 + lane];
        v.x = fmaxf(v.x, n.x * m);
        v.y = fmaxf(v.y, n.y * m);
        v.z = fmaxf(v.z, n.z * m);
        v.w = fmaxf(v.w, n.w * m);
    }

    if (deg == 0) {
        v.x = 0.0f; v.y = 0.0f; v.z = 0.0f; v.w = 0.0f;
    }
    out[base + lane] = v;
}

extern "C" void kernel_launch(void* const* d_in, const int* in_sizes, int n_in,
                              void* d_out, int out_size, void* d_ws, size_t ws_size,
                              hipStream_t stream) {
    const float4* atoms = (const float4*)d_in[0];
    // d_in[1] = bonds (B,A,D,BF) float32 — unused by the reference.
    const int*    edges = (const int*)d_in[2];
    float4*       out   = (float4*)d_out;

    const int nAtoms = NB * NA;            // 16384
    dim3 grid(nAtoms / 4);                 // 4096 blocks
    dim3 block(256);
    NeuralGraphPool_52072183497147_kernel<<<grid, block, 0, stream>>>(atoms, edges, out);
}